// Round 11
// baseline (210.840 us; speedup 1.0000x reference)
//
#include <hip/hip_runtime.h>
#include <stdint.h>

typedef __bf16 bf16;
typedef _Float16 f16;
typedef __bf16 bf16x8 __attribute__((ext_vector_type(8)));
typedef __bf16 bf16x4 __attribute__((ext_vector_type(4)));
typedef float f32x4 __attribute__((ext_vector_type(4)));
typedef float f32x16 __attribute__((ext_vector_type(16)));
typedef _Float16 f16x8 __attribute__((ext_vector_type(8)));
typedef unsigned int u32x4 __attribute__((ext_vector_type(4)));
typedef unsigned int uint2v __attribute__((ext_vector_type(2)));

#define NSEQ 1032
#define BATCH 8
#define NHEADS 12
#define HD 64
#define CDIM 768
#define MROWS (BATCH * NSEQ)   // 8256
#define PREFIX 8
#define NJT 17                 // j-tiles of 64 keys (covers 1088)
#define NQ32 36                // 32-row q groups (covers 1152)
#define KSTRIDE 1152           // padded K rows per head (zeros beyond 1031)
#define VSTRIDE 1152           // padded V^T cols per head (zeros beyond 1031)
// sqrt(0.125 * log2(e)) : folds hd^-0.5 and exp->exp2 into K (both sides of K.K^T).
#define KSCALE 0.42466090f

__device__ __forceinline__ unsigned short f2bf_rne(float f) {
    union { float f; uint32_t u; } v; v.f = f;
    uint32_t u = v.u;
    return (unsigned short)((u + 0x7fffu + ((u >> 16) & 1u)) >> 16);
}

__device__ __forceinline__ void gload_lds16(const bf16* g, bf16* l) {
    __builtin_amdgcn_global_load_lds(
        (const __attribute__((address_space(1))) void*)g,
        (__attribute__((address_space(3))) void*)l, 16, 0, 0);
}

__device__ __forceinline__ unsigned cvtpk(float lo, float hi) {
    unsigned r;
    asm volatile("v_cvt_pk_bf16_f32 %0, %1, %2" : "=v"(r) : "v"(lo), "v"(hi));
    return r;
}

__device__ __forceinline__ void cast4(const float* src, bf16* dst, int i) {
    float4 f = ((const float4*)src)[i];
    ushort4 o;
    o.x = f2bf_rne(f.x); o.y = f2bf_rne(f.y);
    o.z = f2bf_rne(f.z); o.w = f2bf_rne(f.w);
    ((ushort4*)dst)[i] = o;
}

// Raw barrier: drains LDS ops only; global (VMEM) loads stay in flight.
__device__ __forceinline__ void bar() {
    asm volatile("s_waitcnt lgkmcnt(0)" ::: "memory");
    __builtin_amdgcn_s_barrier();
    asm volatile("" ::: "memory");
}

// Counted-wait barrier: wait until <= N VMEM ops outstanding, then sync.
#define VMBAR(N) do { \
        asm volatile("s_waitcnt vmcnt(" #N ")" ::: "memory"); \
        __builtin_amdgcn_s_barrier(); \
        asm volatile("" ::: "memory"); \
    } while (0)

// Fused prep: f16 fragment-linear bias table (32x32 MFMA C layout) + casts
// + K/V^T pad zeroing.
// Bias layout: [grp 36][jt 17][kt 2][lane 64][reg 16] f16, value = log2e*gauss,
// q = grp*32 + (lane&31), k = jt*64 + kt*32 + (reg&3) + 8*(reg>>2) + 4*(lane>>5).
// Per lane: 16 contiguous f16 per kt -> 2 coalesced b128 loads.
__global__ void prep_kernel(const float* __restrict__ x,
                            const float* __restrict__ wkv,
                            const float* __restrict__ pw,
                            bf16* __restrict__ x_bf, bf16* __restrict__ wkv_bf,
                            bf16* __restrict__ pw_bf, f16* __restrict__ Bias,
                            bf16* __restrict__ k_bf, bf16* __restrict__ vt_bf) {
    const int N0 = NQ32 * NJT * 2048;          // bias elems (1,253,376)
    const int N1 = MROWS * CDIM / 4;
    const int N2 = 2 * CDIM * CDIM / 4;
    const int N3 = CDIM * CDIM / 4;
    const int N4 = BATCH * NHEADS * 120 * 8;   // K pad rows 1032..1151, 8 chunks
    const int N5 = BATCH * NHEADS * 64 * 15;   // V^T pad cols 1032..1151
    int i = blockIdx.x * blockDim.x + threadIdx.x;
    if (i < N0) {
        int reg  = i & 15;
        int lane = (i >> 4) & 63;
        int kt   = (i >> 10) & 1;
        int rest = i >> 11;                    // grp*NJT + jt
        int grp  = rest / NJT;
        int jt   = rest - grp * NJT;
        int q = grp * 32 + (lane & 31);
        int k = jt * 64 + kt * 32 + (reg & 3) + 8 * (reg >> 2) + 4 * (lane >> 5);
        float v;
        if (k >= NSEQ) v = -65504.f;           // exp2 -> 0
        else if (q < PREFIX || q >= NSEQ || k < PREFIX) v = 0.f;
        else {
            int rp = q - PREFIX, cp = k - PREFIX;
            int d1 = (rp >> 5) - (cp >> 5);
            int d2 = (rp & 31) - (cp & 31);
            v = 1.44269504f * __expf(-0.02f * (float)(d1 * d1 + d2 * d2));
        }
        Bias[i] = (f16)v;
        return;
    }
    i -= N0;
    if (i < N1) { cast4(x, x_bf, i); return; }
    i -= N1;
    if (i < N2) { cast4(wkv, wkv_bf, i); return; }
    i -= N2;
    if (i < N3) { cast4(pw, pw_bf, i); return; }
    i -= N3;
    if (i < N4) {
        int bh = i / 960, rem = i - bh * 960;
        int row = 1032 + (rem >> 3), ch = rem & 7;
        uint4 z = {0u, 0u, 0u, 0u};
        *(uint4*)&k_bf[((size_t)bh * KSTRIDE + row) * HD + ch * 8] = z;
        return;
    }
    i -= N4;
    if (i < N5) {
        int bh = i / 960, rem = i - bh * 960;
        int d = rem / 15, ch = rem - d * 15;
        uint4 z = {0u, 0u, 0u, 0u};
        *(uint4*)&vt_bf[((size_t)bh * HD + d) * VSTRIDE + 1032 + ch * 8] = z;
    }
}

// NT GEMM, 256x128 tile, 512 threads (8 waves, 4M x 2N), T4 pipeline (frozen
// from round 10): 2 LDS buffers, counted vmcnt(3), bijective XCD swizzle.
template<int EPI>
__global__ __launch_bounds__(512) void gemm_nt(
    const bf16* __restrict__ A, const bf16* __restrict__ B,
    const float* __restrict__ bias,
    float* __restrict__ Cout, bf16* __restrict__ Kout, bf16* __restrict__ Vout,
    int M, int N, int K)
{
    __shared__ bf16 sA[2][256 * 32];
    __shared__ bf16 sB[2][128 * 32];
    const int t = threadIdx.x;
    const int w = t >> 6;
    const int l = t & 63;
    const int quad = l >> 4;
    const int l15 = l & 15;
    const int wy = w >> 1, wx = w & 1;

    const int nbx = gridDim.x;
    int id = blockIdx.y * nbx + blockIdx.x;
    {
        int nwg = nbx * gridDim.y;
        int qq = nwg >> 3, rr = nwg & 7;
        int xcd = id & 7, idx = id >> 3;
        id = (xcd < rr) ? (xcd * (qq + 1) + idx)
                        : (rr * (qq + 1) + (xcd - rr) * qq + idx);
    }
    const int m0 = (id / nbx) * 256;
    const int n0 = (id % nbx) * 128;
    const int co = (quad ^ ((l15 >> 1) & 3)) * 8;

    int r0 = t >> 2;            int c0 = (t & 3) ^ ((r0 >> 1) & 3);
    int r1 = 128 + (t >> 2);    int c1 = (t & 3) ^ ((r1 >> 1) & 3);
    int rB = t >> 2;            int cB = (t & 3) ^ ((rB >> 1) & 3);
    int ra0 = m0 + r0; if (ra0 >= M) ra0 = M - 1;
    int ra1 = m0 + r1; if (ra1 >= M) ra1 = M - 1;
    const bf16* gA0 = A + (size_t)ra0 * K + c0 * 8;
    const bf16* gA1 = A + (size_t)ra1 * K + c1 * 8;
    const bf16* gB0 = B + (size_t)(n0 + rB) * K + cB * 8;
    const int oA0 = (w * 64) * 8;
    const int oA1 = (512 + w * 64) * 8;
    const int oB0 = (w * 64) * 8;

    f32x4 acc[4][4] = {};

#define STAGE(BUF) do { \
        gload_lds16(gA0, &sA[BUF][oA0]); gload_lds16(gA1, &sA[BUF][oA1]); \
        gload_lds16(gB0, &sB[BUF][oB0]); \
        gA0 += 32; gA1 += 32; gB0 += 32; \
    } while (0)

#define COMPUTE(BUF) do { \
        bf16x8 af_[4], bq_[4]; \
        _Pragma("unroll") \
        for (int mt = 0; mt < 4; ++mt) \
            af_[mt] = *(const bf16x8*)&sA[BUF][(wy*64 + mt*16 + l15) * 32 + co]; \
        _Pragma("unroll") \
        for (int nt = 0; nt < 4; ++nt) \
            bq_[nt] = *(const bf16x8*)&sB[BUF][(wx*64 + nt*16 + l15) * 32 + co]; \
        _Pragma("unroll") \
        for (int mt = 0; mt < 4; ++mt) \
            _Pragma("unroll") \
            for (int nt = 0; nt < 4; ++nt) \
                acc[mt][nt] = __builtin_amdgcn_mfma_f32_16x16x32_bf16( \
                    af_[mt], bq_[nt], acc[mt][nt], 0, 0, 0); \
    } while (0)

    const int NT = K / 32;
    STAGE(0);
    STAGE(1);
    VMBAR(3);

    #pragma unroll 1
    for (int p = 0; p <= NT - 4; p += 2) {
        COMPUTE(0);
        bar();
        STAGE(0);
        VMBAR(3);
        COMPUTE(1);
        bar();
        STAGE(1);
        VMBAR(3);
    }
    COMPUTE(0);
    VMBAR(0);
    COMPUTE(1);
#undef STAGE
#undef COMPUTE

    if (EPI == 0) {
        #pragma unroll
        for (int mt = 0; mt < 4; ++mt) {
            #pragma unroll
            for (int r = 0; r < 4; ++r) {
                int m = m0 + wy*64 + mt*16 + quad*4 + r;
                if (m >= M) continue;
                #pragma unroll
                for (int nt = 0; nt < 4; ++nt) {
                    int n = n0 + wx*64 + nt*16 + l15;
                    Cout[(size_t)m * N + n] = acc[mt][nt][r] + bias[n];
                }
            }
        }
    } else {
        #pragma unroll
        for (int mt = 0; mt < 4; ++mt) {
            int mb = m0 + wy*64 + mt*16 + quad*4;
            if (mb >= M) continue;
            int b = mb / NSEQ, s = mb % NSEQ;
            #pragma unroll
            for (int nt = 0; nt < 4; ++nt) {
                int n = n0 + wx*64 + nt*16 + l15;
                float bn = bias[n];
                if (n < CDIM) {
                    int h = n >> 6, d = n & 63;
                    bf16* kp = &Kout[(((size_t)(b*NHEADS + h))*KSTRIDE + s)*HD + d];
                    #pragma unroll
                    for (int r = 0; r < 4; ++r)
                        kp[(size_t)r * HD] = (bf16)((acc[mt][nt][r] + bn) * KSCALE);
                } else {
                    int n2 = n - CDIM;
                    int h = n2 >> 6, d = n2 & 63;
                    bf16x4 pv = { (bf16)(acc[mt][nt][0] + bn), (bf16)(acc[mt][nt][1] + bn),
                                  (bf16)(acc[mt][nt][2] + bn), (bf16)(acc[mt][nt][3] + bn) };
                    *(bf16x4*)&Vout[(((size_t)(b*NHEADS + h))*HD + d)*VSTRIDE + s] = pv;
                }
            }
        }
    }
}

// Attention v2: 32x32 MFMA, 4 waves x 32 q-rows, sP-FREE.
// QK^T: D[key][q], col=lane&31=q, row=(reg&3)+8*(reg>>2)+4*(lane>>5)=key [m74].
// P fragments built in-register: cvt_pk_bf16 pairs + permlane32_swap hands
// lane pairs (l, l+32; same q) each other's 4-key packs -> PV A-frags direct.
// K/V staged via global_load_lds (linear LDS dest, PRE-SWIZZLED global src);
// counted vmcnt(4) double-buffer pipeline. Bias f16 fragment-linear, cvt'd
// straight into the MFMA C operand. Row sums via ones-MFMA (same reg->q map).
__global__ __launch_bounds__(256) void attn_kernel(
    const bf16* __restrict__ Kbuf, const bf16* __restrict__ VTbuf,
    const f16* __restrict__ Bias, bf16* __restrict__ Hout)
{
    const int bh = blockIdx.x;
    const int b = bh / NHEADS, h = bh % NHEADS;
    const int q0 = blockIdx.y * 128;
    const bf16* Kh  = Kbuf  + (size_t)bh * KSTRIDE * HD;   // [s][d]
    const bf16* VTh = VTbuf + (size_t)bh * HD * VSTRIDE;   // [d][s]

    __shared__ bf16 sK[2][64 * 64];    // 8 KB/buf
    __shared__ bf16 sVT[2][64 * 64];   // 8 KB/buf -> 32 KB total

    const int t = threadIdx.x;
    const int w = t >> 6, l = t & 63;
    const int l31 = l & 31, hi = l >> 5;

    // staging: pre-swizzled global sources; LDS dest = wave-uniform base
    // (lane covers base + lane*16). Row r chunk c holds global chunk c^(r&7).
    const int srow = t >> 3;                       // 0..31
    const int sch  = (t & 7) ^ (srow & 7);
    const bf16* gK0 = Kh  + (size_t)srow * HD + sch * 8;
    const bf16* gK1 = Kh  + (size_t)(srow + 32) * HD + sch * 8;
    const bf16* gV0 = VTh + (size_t)srow * VSTRIDE + sch * 8;
    const bf16* gV1 = VTh + (size_t)(srow + 32) * VSTRIDE + sch * 8;
    const int ldst = w * 512;                      // elements (wave-uniform)

    const f16* pB = Bias + ((size_t)(blockIdx.y * 4 + w) * NJT) * 2048 + l * 16;

    // Q fragments: B-operand row = q = l31, k(d) = ks*16 + hi*8
    bf16x8 qf[4];
    {
        int row = q0 + w * 32 + l31;               // < 1152, pad rows zero
        #pragma unroll
        for (int ks = 0; ks < 4; ++ks)
            qf[ks] = *(const bf16x8*)&Kh[(size_t)row * HD + ks * 16 + hi * 8];
    }

    bf16x8 onesb;
    #pragma unroll
    for (int e = 0; e < 8; ++e) onesb[e] = (bf16)1.0f;

    f32x16 Oacc0 = {}, Oacc1 = {}, Lacc = {};
    f16x8 bpf[4];   // bias bank: [kt0 regs0-7, kt0 regs8-15, kt1 r0-7, kt1 r8-15]

#define PREFETCH_B() do { \
        bpf[0] = *(const f16x8*)(pB); \
        bpf[1] = *(const f16x8*)(pB + 8); \
        bpf[2] = *(const f16x8*)(pB + 1024); \
        bpf[3] = *(const f16x8*)(pB + 1032); \
        pB += 2048; \
    } while (0)

#define STAGE(BUF) do { \
        gload_lds16(gK0, &sK[BUF][ldst]); \
        gload_lds16(gK1, &sK[BUF][2048 + ldst]); \
        gload_lds16(gV0, &sVT[BUF][ldst]); \
        gload_lds16(gV1, &sVT[BUF][2048 + ldst]); \
        gK0 += 64 * HD; gK1 += 64 * HD; gV0 += 64; gV1 += 64; \
    } while (0)

    // pack acc(16 p-values) -> 2 PV A-frags (js = 2kt, 2kt+1) via swap
#define PACK(ACC, FA, FB) do { \
        float px[16]; \
        _Pragma("unroll") \
        for (int r_ = 0; r_ < 16; ++r_) px[r_] = __builtin_exp2f(ACC[r_]); \
        unsigned pb0 = cvtpk(px[0], px[1]),   pb1 = cvtpk(px[2], px[3]); \
        unsigned pa0 = cvtpk(px[4], px[5]),   pa1 = cvtpk(px[6], px[7]); \
        uint2v s0 = __builtin_amdgcn_permlane32_swap(pb0, pa0, false, false); \
        uint2v s1 = __builtin_amdgcn_permlane32_swap(pb1, pa1, false, false); \
        u32x4 fa_ = { s0.x, s1.x, s0.y, s1.y }; \
        FA = *(bf16x8*)&fa_; \
        unsigned pc0 = cvtpk(px[8], px[9]),   pc1 = cvtpk(px[10], px[11]); \
        unsigned pd0 = cvtpk(px[12], px[13]), pd1 = cvtpk(px[14], px[15]); \
        uint2v s2 = __builtin_amdgcn_permlane32_swap(pc0, pd0, false, false); \
        uint2v s3 = __builtin_amdgcn_permlane32_swap(pc1, pd1, false, false); \
        u32x4 fb_ = { s2.x, s3.x, s2.y, s3.y }; \
        FB = *(bf16x8*)&fb_; \
    } while (0)

#define COMPUTE(BUF) do { \
        f32x16 a0, a1; \
        _Pragma("unroll") \
        for (int r_ = 0; r_ < 16; ++r_) { \
            a0[r_] = (float)bpf[r_ >> 3][r_ & 7]; \
            a1[r_] = (float)bpf[2 + (r_ >> 3)][r_ & 7]; \
        } \
        PREFETCH_B(); \
        _Pragma("unroll") \
        for (int ks = 0; ks < 4; ++ks) { \
            int c_ = ((ks * 2 + hi) ^ (l31 & 7)) * 8; \
            bf16x8 af0 = *(const bf16x8*)&sK[BUF][l31 * 64 + c_]; \
            bf16x8 af1 = *(const bf16x8*)&sK[BUF][2048 + l31 * 64 + c_]; \
            __builtin_amdgcn_s_setprio(1); \
            a0 = __builtin_amdgcn_mfma_f32_32x32x16_bf16(af0, qf[ks], a0, 0, 0, 0); \
            a1 = __builtin_amdgcn_mfma_f32_32x32x16_bf16(af1, qf[ks], a1, 0, 0, 0); \
            __builtin_amdgcn_s_setprio(0); \
        } \
        bf16x8 pf0, pf1, pf2, pf3; \
        PACK(a0, pf0, pf1); \
        PACK(a1, pf2, pf3); \
        bf16x8 pfr[4] = { pf0, pf1, pf2, pf3 }; \
        _Pragma("unroll") \
        for (int js = 0; js < 4; ++js) { \
            int c_ = ((js * 2 + hi) ^ (l31 & 7)) * 8; \
            bf16x8 bv0 = *(const bf16x8*)&sVT[BUF][l31 * 64 + c_]; \
            bf16x8 bv1 = *(const bf16x8*)&sVT[BUF][2048 + l31 * 64 + c_]; \
            __builtin_amdgcn_s_setprio(1); \
            Oacc0 = __builtin_amdgcn_mfma_f32_32x32x16_bf16(pfr[js], bv0, Oacc0, 0, 0, 0); \
            Oacc1 = __builtin_amdgcn_mfma_f32_32x32x16_bf16(pfr[js], bv1, Oacc1, 0, 0, 0); \
            Lacc  = __builtin_amdgcn_mfma_f32_32x32x16_bf16(pfr[js], onesb, Lacc, 0, 0, 0); \
            __builtin_amdgcn_s_setprio(0); \
        } \
    } while (0)

#define ITER(BUF) do { \
        COMPUTE(BUF); \
        bar(); \
        STAGE(BUF); \
        VMBAR(4); \
    } while (0)

    PREFETCH_B();          // bias tile 0
    STAGE(0);              // tile 0
    STAGE(1);              // tile 1
    VMBAR(4);              // qf+bias0+tile0 complete; tile1 in flight

    ITER(0);               // tile 0, stages tile 2
    #pragma unroll 1
    for (int it = 0; it < 7; ++it) {   // tiles 1..14, stages up to tile 16
        ITER(1);
        ITER(0);
    }
    COMPUTE(1);            // tile 15 (issues bias16)
    VMBAR(0);              // drain stage(16)+bias16
    COMPUTE(0);            // tile 16 (its bias prefetch over-reads into k_bf: harmless)
#undef ITER
#undef COMPUTE
#undef PACK
#undef STAGE
#undef PREFETCH_B

    // epilogue: Oacc/Lacc reg r -> q row (r&3)+8*(r>>2)+4*hi; lane col = d
    #pragma unroll
    for (int r = 0; r < 16; ++r) {
        int q = q0 + w * 32 + (r & 3) + 8 * (r >> 2) + 4 * hi;
        if (q >= NSEQ) continue;
        float inv = 1.f / Lacc[r];
        size_t base = ((size_t)(b * NSEQ) + q) * CDIM + h * HD + l31;
        Hout[base]      = (bf16)(Oacc0[r] * inv);
        Hout[base + 32] = (bf16)(Oacc1[r] * inv);
    }
}

extern "C" void kernel_launch(void* const* d_in, const int* in_sizes, int n_in,
                              void* d_out, int out_size, void* d_ws, size_t ws_size,
                              hipStream_t stream) {
    const float* x      = (const float*)d_in[0];
    const float* qkv_w  = (const float*)d_in[1];
    const float* qkv_b  = (const float*)d_in[2];
    const float* proj_w = (const float*)d_in[3];
    const float* proj_b = (const float*)d_in[4];
    float* out = (float*)d_out;

    char* ws = (char*)d_ws;
    const size_t XBF_BYTES   = (size_t)MROWS * CDIM * 2;                    // 12.68 MB
    const size_t WKV_BYTES   = (size_t)2 * CDIM * CDIM * 2;                 //  2.36 MB
    const size_t PW_BYTES    = (size_t)CDIM * CDIM * 2;                     //  1.18 MB
    const size_t BIAS_BYTES  = (size_t)NQ32 * NJT * 2048 * 2;               //  2.51 MB
    const size_t KBF_BYTES   = (size_t)BATCH * NHEADS * KSTRIDE * HD * 2;   // 14.16 MB

    bf16* x_bf   = (bf16*)ws;
    bf16* wkv_bf = (bf16*)(ws + XBF_BYTES);
    bf16* pw_bf  = (bf16*)(ws + XBF_BYTES + WKV_BYTES);
    f16*  bias_t = (f16*)(ws + XBF_BYTES + WKV_BYTES + PW_BYTES);
    bf16* k_bf   = (bf16*)(ws + XBF_BYTES + WKV_BYTES + PW_BYTES + BIAS_BYTES);
    bf16* vt_bf  = (bf16*)(ws + XBF_BYTES + WKV_BYTES + PW_BYTES + BIAS_BYTES + KBF_BYTES);
    // bias placed before k_bf so the harmless end-of-table bias over-read stays in-bounds

    // fused prep: f16 fragment-linear bias + all casts + K/V^T pad zeroing
    {
        int total = NQ32 * NJT * 2048 + MROWS * CDIM / 4
                  + 2 * CDIM * CDIM / 4 + CDIM * CDIM / 4
                  + BATCH * NHEADS * 120 * 8 + BATCH * NHEADS * 64 * 15;
        prep_kernel<<<dim3((total + 255) / 256), dim3(256), 0, stream>>>(
            x, qkv_w + (size_t)CDIM * CDIM, proj_w, x_bf, wkv_bf, pw_bf, bias_t,
            k_bf, vt_bf);
    }

    // qkv GEMM (k & v only): M=8256, N=1536, K=768 ; writes K' and V^T (padded)
    {
        dim3 grid(1536 / 128, (MROWS + 255) / 256);
        gemm_nt<1><<<grid, dim3(512), 0, stream>>>(x_bf, wkv_bf, qkv_b + CDIM,
                                                   nullptr, k_bf, vt_bf,
                                                   MROWS, 1536, CDIM);
    }

    // attention -> hidden (reuse x_bf buffer); grid (bh, 128-row qtile)
    {
        dim3 grid(BATCH * NHEADS, 9);
        attn_kernel<<<grid, dim3(256), 0, stream>>>(k_bf, vt_bf, bias_t, x_bf);
    }

    // proj GEMM: out = hidden @ proj_w^T + proj_b, fp32 out
    {
        dim3 grid(CDIM / 128, (MROWS + 255) / 256);
        gemm_nt<0><<<grid, dim3(512), 0, stream>>>(x_bf, pw_bf, proj_b,
                                                   out, nullptr, nullptr,
                                                   MROWS, CDIM, CDIM);
    }
}

// Round 12
// 195.471 us; speedup vs baseline: 1.0786x; 1.0786x over previous
//
#include <hip/hip_runtime.h>
#include <stdint.h>

typedef __bf16 bf16;
typedef _Float16 f16;
typedef __bf16 bf16x8 __attribute__((ext_vector_type(8)));
typedef __bf16 bf16x4 __attribute__((ext_vector_type(4)));
typedef float f32x4 __attribute__((ext_vector_type(4)));

#define NSEQ 1032
#define BATCH 8
#define NHEADS 12
#define HD 64
#define CDIM 768
#define MROWS (BATCH * NSEQ)   // 8256
#define PREFIX 8
#define NJT 17                 // j-tiles of 64 keys (covers 1088)
#define NQ16 72                // 16-row q groups (covers 1152)
#define KSTRIDE 1152           // padded K rows per head (zeros beyond 1031)
#define VSTRIDE 1152           // padded V^T cols per head (zeros beyond 1031)
// sqrt(0.125 * log2(e)) : folds hd^-0.5 and exp->exp2 into K (both sides of K.K^T).
#define KSCALE 0.42466090f

__device__ __forceinline__ unsigned short f2bf_rne(float f) {
    union { float f; uint32_t u; } v; v.f = f;
    uint32_t u = v.u;
    return (unsigned short)((u + 0x7fffu + ((u >> 16) & 1u)) >> 16);
}

__device__ __forceinline__ void gload_lds16(const bf16* g, bf16* l) {
    __builtin_amdgcn_global_load_lds(
        (const __attribute__((address_space(1))) void*)g,
        (__attribute__((address_space(3))) void*)l, 16, 0, 0);
}

__device__ __forceinline__ void cast4(const float* src, bf16* dst, int i) {
    float4 f = ((const float4*)src)[i];
    ushort4 o;
    o.x = f2bf_rne(f.x); o.y = f2bf_rne(f.y);
    o.z = f2bf_rne(f.z); o.w = f2bf_rne(f.w);
    ((ushort4*)dst)[i] = o;
}

// Raw barrier: drains LDS ops only; global (VMEM) loads stay in flight.
__device__ __forceinline__ void bar() {
    asm volatile("s_waitcnt lgkmcnt(0)" ::: "memory");
    __builtin_amdgcn_s_barrier();
    asm volatile("" ::: "memory");
}

// Counted-wait barrier: wait until <= N VMEM ops outstanding, then sync.
#define VMBAR(N) do { \
        asm volatile("s_waitcnt vmcnt(" #N ")" ::: "memory"); \
        __builtin_amdgcn_s_barrier(); \
        asm volatile("" ::: "memory"); \
    } while (0)

// Fused prep: f32 fragment-linear bias table + casts + K/V^T pad zeroing.
// Bias layout: [q16][jt][kt][quad][l15][r] f32, value = log2e * gauss(q,k),
// q = q16*16+l15, k = jt*64+kt*16+quad*4+r -> one coalesced b128/lane/fragment.
__global__ void prep_kernel(const float* __restrict__ x,
                            const float* __restrict__ wkv,
                            const float* __restrict__ pw,
                            bf16* __restrict__ x_bf, bf16* __restrict__ wkv_bf,
                            bf16* __restrict__ pw_bf, float* __restrict__ Bias,
                            bf16* __restrict__ k_bf, bf16* __restrict__ vt_bf) {
    const int N0 = NQ16 * NJT * 1024;          // bias elems
    const int N1 = MROWS * CDIM / 4;
    const int N2 = 2 * CDIM * CDIM / 4;
    const int N3 = CDIM * CDIM / 4;
    const int N4 = BATCH * NHEADS * 120 * 8;   // K pad rows 1032..1151, 8 chunks
    const int N5 = BATCH * NHEADS * 64 * 15;   // V^T pad cols 1032..1151
    int i = blockIdx.x * blockDim.x + threadIdx.x;
    if (i < N0) {
        int r    = i & 3;
        int l15  = (i >> 2) & 15;
        int quad = (i >> 6) & 3;
        int kt   = (i >> 8) & 3;
        int rest = i >> 10;                    // q16*NJT + jt
        int q16  = rest / NJT;
        int jt   = rest - q16 * NJT;
        int q = q16 * 16 + l15;
        int k = jt * 64 + kt * 16 + quad * 4 + r;
        float v;
        if (k >= NSEQ) v = -65504.f;           // exp2 -> 0
        else if (q < PREFIX || q >= NSEQ || k < PREFIX) v = 0.f;
        else {
            int rp = q - PREFIX, cp = k - PREFIX;
            int d1 = (rp >> 5) - (cp >> 5);
            int d2 = (rp & 31) - (cp & 31);
            v = 1.44269504f * __expf(-0.02f * (float)(d1 * d1 + d2 * d2));
        }
        Bias[i] = v;
        return;
    }
    i -= N0;
    if (i < N1) { cast4(x, x_bf, i); return; }
    i -= N1;
    if (i < N2) { cast4(wkv, wkv_bf, i); return; }
    i -= N2;
    if (i < N3) { cast4(pw, pw_bf, i); return; }
    i -= N3;
    if (i < N4) {
        int bh = i / 960, rem = i - bh * 960;
        int row = 1032 + (rem >> 3), ch = rem & 7;
        uint4 z = {0u, 0u, 0u, 0u};
        *(uint4*)&k_bf[((size_t)bh * KSTRIDE + row) * HD + ch * 8] = z;
        return;
    }
    i -= N4;
    if (i < N5) {
        int bh = i / 960, rem = i - bh * 960;
        int d = rem / 15, ch = rem - d * 15;
        uint4 z = {0u, 0u, 0u, 0u};
        *(uint4*)&vt_bf[((size_t)bh * HD + d) * VSTRIDE + 1032 + ch * 8] = z;
    }
}

// NT GEMM, 256x128 tile, 512 threads (8 waves, 4M x 2N), T4 pipeline (frozen
// from round 10): 2 LDS buffers, counted vmcnt(3), bijective XCD swizzle.
template<int EPI>
__global__ __launch_bounds__(512) void gemm_nt(
    const bf16* __restrict__ A, const bf16* __restrict__ B,
    const float* __restrict__ bias,
    float* __restrict__ Cout, bf16* __restrict__ Kout, bf16* __restrict__ Vout,
    int M, int N, int K)
{
    __shared__ bf16 sA[2][256 * 32];
    __shared__ bf16 sB[2][128 * 32];
    const int t = threadIdx.x;
    const int w = t >> 6;
    const int l = t & 63;
    const int quad = l >> 4;
    const int l15 = l & 15;
    const int wy = w >> 1, wx = w & 1;

    const int nbx = gridDim.x;
    int id = blockIdx.y * nbx + blockIdx.x;
    {
        int nwg = nbx * gridDim.y;
        int qq = nwg >> 3, rr = nwg & 7;
        int xcd = id & 7, idx = id >> 3;
        id = (xcd < rr) ? (xcd * (qq + 1) + idx)
                        : (rr * (qq + 1) + (xcd - rr) * qq + idx);
    }
    const int m0 = (id / nbx) * 256;
    const int n0 = (id % nbx) * 128;
    const int co = (quad ^ ((l15 >> 1) & 3)) * 8;

    int r0 = t >> 2;            int c0 = (t & 3) ^ ((r0 >> 1) & 3);
    int r1 = 128 + (t >> 2);    int c1 = (t & 3) ^ ((r1 >> 1) & 3);
    int rB = t >> 2;            int cB = (t & 3) ^ ((rB >> 1) & 3);
    int ra0 = m0 + r0; if (ra0 >= M) ra0 = M - 1;
    int ra1 = m0 + r1; if (ra1 >= M) ra1 = M - 1;
    const bf16* gA0 = A + (size_t)ra0 * K + c0 * 8;
    const bf16* gA1 = A + (size_t)ra1 * K + c1 * 8;
    const bf16* gB0 = B + (size_t)(n0 + rB) * K + cB * 8;
    const int oA0 = (w * 64) * 8;
    const int oA1 = (512 + w * 64) * 8;
    const int oB0 = (w * 64) * 8;

    f32x4 acc[4][4] = {};

#define STAGE(BUF) do { \
        gload_lds16(gA0, &sA[BUF][oA0]); gload_lds16(gA1, &sA[BUF][oA1]); \
        gload_lds16(gB0, &sB[BUF][oB0]); \
        gA0 += 32; gA1 += 32; gB0 += 32; \
    } while (0)

#define COMPUTE(BUF) do { \
        bf16x8 af_[4], bq_[4]; \
        _Pragma("unroll") \
        for (int mt = 0; mt < 4; ++mt) \
            af_[mt] = *(const bf16x8*)&sA[BUF][(wy*64 + mt*16 + l15) * 32 + co]; \
        _Pragma("unroll") \
        for (int nt = 0; nt < 4; ++nt) \
            bq_[nt] = *(const bf16x8*)&sB[BUF][(wx*64 + nt*16 + l15) * 32 + co]; \
        _Pragma("unroll") \
        for (int mt = 0; mt < 4; ++mt) \
            _Pragma("unroll") \
            for (int nt = 0; nt < 4; ++nt) \
                acc[mt][nt] = __builtin_amdgcn_mfma_f32_16x16x32_bf16( \
                    af_[mt], bq_[nt], acc[mt][nt], 0, 0, 0); \
    } while (0)

    const int NT = K / 32;
    STAGE(0);
    STAGE(1);
    VMBAR(3);

    #pragma unroll 1
    for (int p = 0; p <= NT - 4; p += 2) {
        COMPUTE(0);
        bar();
        STAGE(0);
        VMBAR(3);
        COMPUTE(1);
        bar();
        STAGE(1);
        VMBAR(3);
    }
    COMPUTE(0);
    VMBAR(0);
    COMPUTE(1);
#undef STAGE
#undef COMPUTE

    if (EPI == 0) {
        #pragma unroll
        for (int mt = 0; mt < 4; ++mt) {
            #pragma unroll
            for (int r = 0; r < 4; ++r) {
                int m = m0 + wy*64 + mt*16 + quad*4 + r;
                if (m >= M) continue;
                #pragma unroll
                for (int nt = 0; nt < 4; ++nt) {
                    int n = n0 + wx*64 + nt*16 + l15;
                    Cout[(size_t)m * N + n] = acc[mt][nt][r] + bias[n];
                }
            }
        }
    } else {
        #pragma unroll
        for (int mt = 0; mt < 4; ++mt) {
            int mb = m0 + wy*64 + mt*16 + quad*4;
            if (mb >= M) continue;
            int b = mb / NSEQ, s = mb % NSEQ;
            #pragma unroll
            for (int nt = 0; nt < 4; ++nt) {
                int n = n0 + wx*64 + nt*16 + l15;
                float bn = bias[n];
                if (n < CDIM) {
                    int h = n >> 6, d = n & 63;
                    bf16* kp = &Kout[(((size_t)(b*NHEADS + h))*KSTRIDE + s)*HD + d];
                    #pragma unroll
                    for (int r = 0; r < 4; ++r)
                        kp[(size_t)r * HD] = (bf16)((acc[mt][nt][r] + bn) * KSCALE);
                } else {
                    int n2 = n - CDIM;
                    int h = n2 >> 6, d = n2 & 63;
                    bf16x4 pv = { (bf16)(acc[mt][nt][0] + bn), (bf16)(acc[mt][nt][1] + bn),
                                  (bf16)(acc[mt][nt][2] + bn), (bf16)(acc[mt][nt][3] + bn) };
                    *(bf16x4*)&Vout[(((size_t)(b*NHEADS + h))*HD + d)*VSTRIDE + s] = pv;
                }
            }
        }
    }
}

// Attention (round-10 structure, reverted from 32x32 experiment): 8 waves x
// 16 q-rows (128 q/block), double-buffered swizzled reg-staging, clamp-free
// pointer bumps, f32 bias banks accumulated directly by QK^T MFMA, ones-MFMA
// row sums. NEW: wave-uniform `wactive` guard — waves whose entire 16-row
// q-range is padding (7/8 waves in the y=8 blocks) run staging+barriers only,
// skipping all compute (~10% of attn block-work).
__global__ __launch_bounds__(512) void attn_kernel(
    const bf16* __restrict__ Kbuf, const bf16* __restrict__ VTbuf,
    const float* __restrict__ Bias, bf16* __restrict__ Hout)
{
    const int bh = blockIdx.x;                  // same-bh blocks land on one XCD (96%8==0)
    const int b = bh / NHEADS, h = bh % NHEADS;
    const int q0 = blockIdx.y * 128;
    const bf16* Kh  = Kbuf  + (size_t)bh * KSTRIDE * HD;   // [s][d]
    const bf16* VTh = VTbuf + (size_t)bh * HD * VSTRIDE;   // [d][s]

    __shared__ bf16 sK[2][64 * 64];    // 8 KB/buf
    __shared__ bf16 sVT[2][64 * 64];   // 8 KB/buf
    __shared__ bf16 sP[128 * 64];      // 16 KB -> 48 KB total (3 blocks/CU)

    const int t = threadIdx.x;
    const int w = t >> 6, l = t & 63, quad = l >> 4, l15 = l & 15;
    const int sw = l15 & 7;

    // wave-uniform: does this wave own any valid q-row?
    const bool wactive = (q0 + w * 16) < NSEQ;

    // staging geometry: 1 swizzled b128 chunk per thread per buffer
    const int r0 = t >> 3, c0 = t & 7;              // r0: 0..63, c0: 0..7
    const int dk0 = r0*64 + ((c0 ^ (r0 & 7)) << 3);

    // clamp-free global pointers (pure bumps; pads make every tile safe)
    const bf16* pK0 = Kh + (size_t)r0 * HD + c0 * 8;
    const bf16* pV0 = VTh + (size_t)r0 * VSTRIDE + c0 * 8;
    const float* pB = Bias + (size_t)(blockIdx.y*8 + w) * NJT * 1024 + quad*64 + l15*4;

    // Q fragments (B-operand), 16 query rows per wave; queries = keys.
    bf16x8 qf[2];
    {
        int row = q0 + w*16 + l15;              // < 1152, pad rows are zero
        #pragma unroll
        for (int ks = 0; ks < 2; ++ks)
            qf[ks] = *(const bf16x8*)&Kh[(size_t)row * HD + ks*32 + quad*8];
    }

    bf16x8 onesb;
    #pragma unroll
    for (int e = 0; e < 8; ++e) onesb[e] = (bf16)1.0f;

    f32x4 Oacc[4] = {};
    f32x4 Lacc = {};
    const int sPr0 = (w*16 + l15) * 64;

    uint4 kva, vva;
    f32x4 bpA[4], bpB[4];   // named bias banks (compile-time indexed)

#define PREFETCH_KV() do { \
        kva = *(const uint4*)pK0; \
        vva = *(const uint4*)pV0; \
        pK0 += 64*HD; pV0 += 64; \
    } while (0)

#define PREFETCH_B(BANK) do { \
        _Pragma("unroll") \
        for (int kt = 0; kt < 4; ++kt) \
            BANK[kt] = *(const f32x4*)(pB + kt*256); \
        pB += 1024; \
    } while (0)

#define ITER(CUR, ACC, NEXT) do { \
        *(uint4*)&sK[CUR][dk0] = kva; \
        *(uint4*)&sVT[CUR][dk0] = vva; \
        PREFETCH_KV(); \
        PREFETCH_B(NEXT); \
        bar(); \
        if (wactive) { \
            _Pragma("unroll") \
            for (int ks = 0; ks < 2; ++ks) { \
                bf16x8 af[4]; \
                _Pragma("unroll") \
                for (int kt = 0; kt < 4; ++kt) \
                    af[kt] = *(const bf16x8*)&sK[CUR][(kt*16 + l15)*64 + (((ks*4 + quad) ^ sw) << 3)]; \
                __builtin_amdgcn_s_setprio(1); \
                _Pragma("unroll") \
                for (int kt = 0; kt < 4; ++kt) \
                    ACC[kt] = __builtin_amdgcn_mfma_f32_16x16x32_bf16( \
                        af[kt], qf[ks], ACC[kt], 0, 0, 0); \
                __builtin_amdgcn_s_setprio(0); \
            } \
            _Pragma("unroll") \
            for (int kt = 0; kt < 4; ++kt) { \
                float p0 = __builtin_exp2f(ACC[kt][0]); \
                float p1 = __builtin_exp2f(ACC[kt][1]); \
                float p2 = __builtin_exp2f(ACC[kt][2]); \
                float p3 = __builtin_exp2f(ACC[kt][3]); \
                bf16x4 pv = { (bf16)p0, (bf16)p1, (bf16)p2, (bf16)p3 }; \
                int g = (kt*2 + (quad >> 1)) ^ sw; \
                *(bf16x4*)&sP[sPr0 + g*8 + (quad & 1)*4] = pv; \
            } \
            _Pragma("unroll") \
            for (int ks = 0; ks < 2; ++ks) { \
                bf16x8 bv[4]; \
                _Pragma("unroll") \
                for (int dt = 0; dt < 4; ++dt) \
                    bv[dt] = *(const bf16x8*)&sVT[CUR][(dt*16 + l15)*64 + (((ks*4 + quad) ^ sw) << 3)]; \
                __builtin_amdgcn_s_setprio(1); \
                bf16x8 ap = *(const bf16x8*)&sP[sPr0 + (((ks*4 + quad) ^ sw) * 8)]; \
                _Pragma("unroll") \
                for (int dt = 0; dt < 4; ++dt) \
                    Oacc[dt] = __builtin_amdgcn_mfma_f32_16x16x32_bf16( \
                        ap, bv[dt], Oacc[dt], 0, 0, 0); \
                Lacc = __builtin_amdgcn_mfma_f32_16x16x32_bf16( \
                    ap, onesb, Lacc, 0, 0, 0); \
                __builtin_amdgcn_s_setprio(0); \
            } \
        } \
    } while (0)

    PREFETCH_KV();        // tile 0 K/V
    PREFETCH_B(bpA);      // tile 0 bias -> bank A
    ITER(0, bpA, bpB);    // jt 0
    #pragma unroll 1
    for (int it = 0; it < (NJT - 1) / 2; ++it) {   // jt 1..16 as 8 pairs
        ITER(1, bpB, bpA);
        ITER(0, bpA, bpB);
    }
#undef ITER
#undef PREFETCH_KV
#undef PREFETCH_B

    // epilogue: Lacc holds per-row sums (rows quad*4+r) lane-locally
    #pragma unroll
    for (int r = 0; r < 4; ++r) {
        int g = q0 + w*16 + quad*4 + r;
        if (g >= NSEQ) continue;
        float inv = 1.f / Lacc[r];
        size_t base = ((size_t)(b * NSEQ) + g) * CDIM + h * HD;
        #pragma unroll
        for (int dt = 0; dt < 4; ++dt)
            Hout[base + dt*16 + l15] = (bf16)(Oacc[dt][r] * inv);
    }
}

extern "C" void kernel_launch(void* const* d_in, const int* in_sizes, int n_in,
                              void* d_out, int out_size, void* d_ws, size_t ws_size,
                              hipStream_t stream) {
    const float* x      = (const float*)d_in[0];
    const float* qkv_w  = (const float*)d_in[1];
    const float* qkv_b  = (const float*)d_in[2];
    const float* proj_w = (const float*)d_in[3];
    const float* proj_b = (const float*)d_in[4];
    float* out = (float*)d_out;

    char* ws = (char*)d_ws;
    const size_t XBF_BYTES   = (size_t)MROWS * CDIM * 2;                    // 12.68 MB
    const size_t WKV_BYTES   = (size_t)2 * CDIM * CDIM * 2;                 //  2.36 MB
    const size_t PW_BYTES    = (size_t)CDIM * CDIM * 2;                     //  1.18 MB
    const size_t BIAS_BYTES  = (size_t)NQ16 * NJT * 1024 * 4;               //  5.01 MB
    const size_t KBF_BYTES   = (size_t)BATCH * NHEADS * KSTRIDE * HD * 2;   // 14.16 MB

    bf16*  x_bf   = (bf16*)ws;
    bf16*  wkv_bf = (bf16*)(ws + XBF_BYTES);
    bf16*  pw_bf  = (bf16*)(ws + XBF_BYTES + WKV_BYTES);
    float* bias_t = (float*)(ws + XBF_BYTES + WKV_BYTES + PW_BYTES);
    bf16*  k_bf   = (bf16*)(ws + XBF_BYTES + WKV_BYTES + PW_BYTES + BIAS_BYTES);
    bf16*  vt_bf  = (bf16*)(ws + XBF_BYTES + WKV_BYTES + PW_BYTES + BIAS_BYTES + KBF_BYTES);
    // bias placed before k_bf so the harmless end-of-table bias over-read stays in-bounds

    // fused prep: f32 fragment-linear bias + all casts + K/V^T pad zeroing
    {
        int total = NQ16 * NJT * 1024 + MROWS * CDIM / 4
                  + 2 * CDIM * CDIM / 4 + CDIM * CDIM / 4
                  + BATCH * NHEADS * 120 * 8 + BATCH * NHEADS * 64 * 15;
        prep_kernel<<<dim3((total + 255) / 256), dim3(256), 0, stream>>>(
            x, qkv_w + (size_t)CDIM * CDIM, proj_w, x_bf, wkv_bf, pw_bf, bias_t,
            k_bf, vt_bf);
    }

    // qkv GEMM (k & v only): M=8256, N=1536, K=768 ; writes K' and V^T (padded)
    {
        dim3 grid(1536 / 128, (MROWS + 255) / 256);
        gemm_nt<1><<<grid, dim3(512), 0, stream>>>(x_bf, wkv_bf, qkv_b + CDIM,
                                                   nullptr, k_bf, vt_bf,
                                                   MROWS, 1536, CDIM);
    }

    // attention -> hidden (reuse x_bf buffer); grid (bh, 128-row qtile)
    {
        dim3 grid(BATCH * NHEADS, 9);
        attn_kernel<<<grid, dim3(512), 0, stream>>>(k_bf, vt_bf, bias_t, x_bf);
    }

    // proj GEMM: out = hidden @ proj_w^T + proj_b, fp32 out
    {
        dim3 grid(CDIM / 128, (MROWS + 255) / 256);
        gemm_nt<0><<<grid, dim3(512), 0, stream>>>(x_bf, pw_bf, proj_b,
                                                   out, nullptr, nullptr,
                                                   MROWS, CDIM, CDIM);
    }
}

// Round 13
// 191.491 us; speedup vs baseline: 1.1010x; 1.0208x over previous
//
#include <hip/hip_runtime.h>
#include <stdint.h>

typedef __bf16 bf16;
typedef _Float16 f16;
typedef __bf16 bf16x8 __attribute__((ext_vector_type(8)));
typedef __bf16 bf16x4 __attribute__((ext_vector_type(4)));
typedef float f32x4 __attribute__((ext_vector_type(4)));

#define NSEQ 1032
#define BATCH 8
#define NHEADS 12
#define HD 64
#define CDIM 768
#define MROWS (BATCH * NSEQ)   // 8256
#define PREFIX 8
#define NJT 17                 // j-tiles of 64 keys (covers 1088)
#define NQ16 72                // 16-row q groups (covers 1152)
#define KSTRIDE 1152           // padded K rows per head (zeros beyond 1031)
#define VSTRIDE 1152           // padded V^T cols per head (zeros beyond 1031)
// sqrt(0.125 * log2(e)) : folds hd^-0.5 and exp->exp2 into K (both sides of K.K^T).
#define KSCALE 0.42466090f

__device__ __forceinline__ unsigned short f2bf_rne(float f) {
    union { float f; uint32_t u; } v; v.f = f;
    uint32_t u = v.u;
    return (unsigned short)((u + 0x7fffu + ((u >> 16) & 1u)) >> 16);
}

__device__ __forceinline__ void gload_lds16(const bf16* g, bf16* l) {
    __builtin_amdgcn_global_load_lds(
        (const __attribute__((address_space(1))) void*)g,
        (__attribute__((address_space(3))) void*)l, 16, 0, 0);
}

__device__ __forceinline__ void cast4(const float* src, bf16* dst, int i) {
    float4 f = ((const float4*)src)[i];
    ushort4 o;
    o.x = f2bf_rne(f.x); o.y = f2bf_rne(f.y);
    o.z = f2bf_rne(f.z); o.w = f2bf_rne(f.w);
    ((ushort4*)dst)[i] = o;
}

// Raw barrier: drains LDS ops only; global (VMEM) loads stay in flight.
__device__ __forceinline__ void bar() {
    asm volatile("s_waitcnt lgkmcnt(0)" ::: "memory");
    __builtin_amdgcn_s_barrier();
    asm volatile("" ::: "memory");
}

// Counted-wait barrier: wait until <= N VMEM ops outstanding, then sync.
#define VMBAR(N) do { \
        asm volatile("s_waitcnt vmcnt(" #N ")" ::: "memory"); \
        __builtin_amdgcn_s_barrier(); \
        asm volatile("" ::: "memory"); \
    } while (0)

// Fused prep: f32 fragment-linear bias table + casts + K/V^T pad zeroing.
// Bias layout: [q16][jt][kt][quad][l15][r] f32, value = log2e * gauss(q,k),
// q = q16*16+l15, k = jt*64+kt*16+quad*4+r -> one coalesced b128/lane/fragment.
__global__ void prep_kernel(const float* __restrict__ x,
                            const float* __restrict__ wkv,
                            const float* __restrict__ pw,
                            bf16* __restrict__ x_bf, bf16* __restrict__ wkv_bf,
                            bf16* __restrict__ pw_bf, float* __restrict__ Bias,
                            bf16* __restrict__ k_bf, bf16* __restrict__ vt_bf) {
    const int N0 = NQ16 * NJT * 1024;          // bias elems
    const int N1 = MROWS * CDIM / 4;
    const int N2 = 2 * CDIM * CDIM / 4;
    const int N3 = CDIM * CDIM / 4;
    const int N4 = BATCH * NHEADS * 120 * 8;   // K pad rows 1032..1151, 8 chunks
    const int N5 = BATCH * NHEADS * 64 * 15;   // V^T pad cols 1032..1151
    int i = blockIdx.x * blockDim.x + threadIdx.x;
    if (i < N0) {
        int r    = i & 3;
        int l15  = (i >> 2) & 15;
        int quad = (i >> 6) & 3;
        int kt   = (i >> 8) & 3;
        int rest = i >> 10;                    // q16*NJT + jt
        int q16  = rest / NJT;
        int jt   = rest - q16 * NJT;
        int q = q16 * 16 + l15;
        int k = jt * 64 + kt * 16 + quad * 4 + r;
        float v;
        if (k >= NSEQ) v = -65504.f;           // exp2 -> 0
        else if (q < PREFIX || q >= NSEQ || k < PREFIX) v = 0.f;
        else {
            int rp = q - PREFIX, cp = k - PREFIX;
            int d1 = (rp >> 5) - (cp >> 5);
            int d2 = (rp & 31) - (cp & 31);
            v = 1.44269504f * __expf(-0.02f * (float)(d1 * d1 + d2 * d2));
        }
        Bias[i] = v;
        return;
    }
    i -= N0;
    if (i < N1) { cast4(x, x_bf, i); return; }
    i -= N1;
    if (i < N2) { cast4(wkv, wkv_bf, i); return; }
    i -= N2;
    if (i < N3) { cast4(pw, pw_bf, i); return; }
    i -= N3;
    if (i < N4) {
        int bh = i / 960, rem = i - bh * 960;
        int row = 1032 + (rem >> 3), ch = rem & 7;
        uint4 z = {0u, 0u, 0u, 0u};
        *(uint4*)&k_bf[((size_t)bh * KSTRIDE + row) * HD + ch * 8] = z;
        return;
    }
    i -= N4;
    if (i < N5) {
        int bh = i / 960, rem = i - bh * 960;
        int d = rem / 15, ch = rem - d * 15;
        uint4 z = {0u, 0u, 0u, 0u};
        *(uint4*)&vt_bf[((size_t)bh * HD + d) * VSTRIDE + 1032 + ch * 8] = z;
    }
}

// NT GEMM, 256x128 tile, 512 threads (8 waves, 4M x 2N), T4 pipeline (frozen
// from round 10): 2 LDS buffers, counted vmcnt(3), bijective XCD swizzle.
// Used for qkv (EPI=1): grid 12x33 = 396 blocks, ~2 blocks/CU resident.
template<int EPI>
__global__ __launch_bounds__(512) void gemm_nt(
    const bf16* __restrict__ A, const bf16* __restrict__ B,
    const float* __restrict__ bias,
    float* __restrict__ Cout, bf16* __restrict__ Kout, bf16* __restrict__ Vout,
    int M, int N, int K)
{
    __shared__ bf16 sA[2][256 * 32];
    __shared__ bf16 sB[2][128 * 32];
    const int t = threadIdx.x;
    const int w = t >> 6;
    const int l = t & 63;
    const int quad = l >> 4;
    const int l15 = l & 15;
    const int wy = w >> 1, wx = w & 1;

    const int nbx = gridDim.x;
    int id = blockIdx.y * nbx + blockIdx.x;
    {
        int nwg = nbx * gridDim.y;
        int qq = nwg >> 3, rr = nwg & 7;
        int xcd = id & 7, idx = id >> 3;
        id = (xcd < rr) ? (xcd * (qq + 1) + idx)
                        : (rr * (qq + 1) + (xcd - rr) * qq + idx);
    }
    const int m0 = (id / nbx) * 256;
    const int n0 = (id % nbx) * 128;
    const int co = (quad ^ ((l15 >> 1) & 3)) * 8;

    int r0 = t >> 2;            int c0 = (t & 3) ^ ((r0 >> 1) & 3);
    int r1 = 128 + (t >> 2);    int c1 = (t & 3) ^ ((r1 >> 1) & 3);
    int rB = t >> 2;            int cB = (t & 3) ^ ((rB >> 1) & 3);
    int ra0 = m0 + r0; if (ra0 >= M) ra0 = M - 1;
    int ra1 = m0 + r1; if (ra1 >= M) ra1 = M - 1;
    const bf16* gA0 = A + (size_t)ra0 * K + c0 * 8;
    const bf16* gA1 = A + (size_t)ra1 * K + c1 * 8;
    const bf16* gB0 = B + (size_t)(n0 + rB) * K + cB * 8;
    const int oA0 = (w * 64) * 8;
    const int oA1 = (512 + w * 64) * 8;
    const int oB0 = (w * 64) * 8;

    f32x4 acc[4][4] = {};

#define STAGE(BUF) do { \
        gload_lds16(gA0, &sA[BUF][oA0]); gload_lds16(gA1, &sA[BUF][oA1]); \
        gload_lds16(gB0, &sB[BUF][oB0]); \
        gA0 += 32; gA1 += 32; gB0 += 32; \
    } while (0)

#define COMPUTE(BUF) do { \
        bf16x8 af_[4], bq_[4]; \
        _Pragma("unroll") \
        for (int mt = 0; mt < 4; ++mt) \
            af_[mt] = *(const bf16x8*)&sA[BUF][(wy*64 + mt*16 + l15) * 32 + co]; \
        _Pragma("unroll") \
        for (int nt = 0; nt < 4; ++nt) \
            bq_[nt] = *(const bf16x8*)&sB[BUF][(wx*64 + nt*16 + l15) * 32 + co]; \
        _Pragma("unroll") \
        for (int mt = 0; mt < 4; ++mt) \
            _Pragma("unroll") \
            for (int nt = 0; nt < 4; ++nt) \
                acc[mt][nt] = __builtin_amdgcn_mfma_f32_16x16x32_bf16( \
                    af_[mt], bq_[nt], acc[mt][nt], 0, 0, 0); \
    } while (0)

    const int NT = K / 32;
    STAGE(0);
    STAGE(1);
    VMBAR(3);

    #pragma unroll 1
    for (int p = 0; p <= NT - 4; p += 2) {
        COMPUTE(0);
        bar();
        STAGE(0);
        VMBAR(3);
        COMPUTE(1);
        bar();
        STAGE(1);
        VMBAR(3);
    }
    COMPUTE(0);
    VMBAR(0);
    COMPUTE(1);
#undef STAGE
#undef COMPUTE

    if (EPI == 0) {
        #pragma unroll
        for (int mt = 0; mt < 4; ++mt) {
            #pragma unroll
            for (int r = 0; r < 4; ++r) {
                int m = m0 + wy*64 + mt*16 + quad*4 + r;
                if (m >= M) continue;
                #pragma unroll
                for (int nt = 0; nt < 4; ++nt) {
                    int n = n0 + wx*64 + nt*16 + l15;
                    Cout[(size_t)m * N + n] = acc[mt][nt][r] + bias[n];
                }
            }
        }
    } else {
        #pragma unroll
        for (int mt = 0; mt < 4; ++mt) {
            int mb = m0 + wy*64 + mt*16 + quad*4;
            if (mb >= M) continue;
            int b = mb / NSEQ, s = mb % NSEQ;
            #pragma unroll
            for (int nt = 0; nt < 4; ++nt) {
                int n = n0 + wx*64 + nt*16 + l15;
                float bn = bias[n];
                if (n < CDIM) {
                    int h = n >> 6, d = n & 63;
                    bf16* kp = &Kout[(((size_t)(b*NHEADS + h))*KSTRIDE + s)*HD + d];
                    #pragma unroll
                    for (int r = 0; r < 4; ++r)
                        kp[(size_t)r * HD] = (bf16)((acc[mt][nt][r] + bn) * KSCALE);
                } else {
                    int n2 = n - CDIM;
                    int h = n2 >> 6, d = n2 & 63;
                    bf16x4 pv = { (bf16)(acc[mt][nt][0] + bn), (bf16)(acc[mt][nt][1] + bn),
                                  (bf16)(acc[mt][nt][2] + bn), (bf16)(acc[mt][nt][3] + bn) };
                    *(bf16x4*)&Vout[(((size_t)(b*NHEADS + h))*HD + d)*VSTRIDE + s] = pv;
                }
            }
        }
    }
}

// NT GEMM, 128x128 tile, 256 threads (4 waves), round-9-proven T4 pipeline
// (4 loads/stage, vmcnt(4)) + XCD swizzle. Used for proj: the 256-row tile
// gives proj only 198 blocks (< 256 CUs, 1/4 of the GPU idle); this variant
// gives 390 blocks at ~4 blocks/CU resident and half the per-block latency.
__global__ __launch_bounds__(256) void gemm_nt128(
    const bf16* __restrict__ A, const bf16* __restrict__ B,
    const float* __restrict__ bias,
    float* __restrict__ Cout, int M, int N, int K)
{
    __shared__ bf16 sA[2][128 * 32];
    __shared__ bf16 sB[2][128 * 32];
    const int t = threadIdx.x;
    const int w = t >> 6;
    const int l = t & 63;
    const int quad = l >> 4;
    const int l15 = l & 15;
    const int wy = w >> 1, wx = w & 1;

    const int nbx = gridDim.x;
    int id = blockIdx.y * nbx + blockIdx.x;
    {
        int nwg = nbx * gridDim.y;
        int qq = nwg >> 3, rr = nwg & 7;
        int xcd = id & 7, idx = id >> 3;
        id = (xcd < rr) ? (xcd * (qq + 1) + idx)
                        : (rr * (qq + 1) + (xcd - rr) * qq + idx);
    }
    const int m0 = (id / nbx) * 128;
    const int n0 = (id % nbx) * 128;
    const int co = (quad ^ ((l15 >> 1) & 3)) * 8;

    int r0 = t >> 2,          c0 = (t & 3) ^ ((r0 >> 1) & 3);
    int r1 = (t + 256) >> 2,  c1 = ((t + 256) & 3) ^ ((r1 >> 1) & 3);
    int ra0 = m0 + r0; if (ra0 >= M) ra0 = M - 1;
    int ra1 = m0 + r1; if (ra1 >= M) ra1 = M - 1;
    const bf16* gA0 = A + (size_t)ra0 * K + c0 * 8;
    const bf16* gA1 = A + (size_t)ra1 * K + c1 * 8;
    const bf16* gB0 = B + (size_t)(n0 + r0) * K + c0 * 8;
    const bf16* gB1 = B + (size_t)(n0 + r1) * K + c1 * 8;
    const int oA0 = (w * 64) * 8;
    const int oA1 = (256 + w * 64) * 8;

    f32x4 acc[4][4] = {};

#define STAGE(BUF) do { \
        gload_lds16(gA0, &sA[BUF][oA0]); gload_lds16(gA1, &sA[BUF][oA1]); \
        gload_lds16(gB0, &sB[BUF][oA0]); gload_lds16(gB1, &sB[BUF][oA1]); \
        gA0 += 32; gA1 += 32; gB0 += 32; gB1 += 32; \
    } while (0)

#define COMPUTE(BUF) do { \
        bf16x8 af_[4], bq_[4]; \
        _Pragma("unroll") \
        for (int mt = 0; mt < 4; ++mt) \
            af_[mt] = *(const bf16x8*)&sA[BUF][(wy*64 + mt*16 + l15) * 32 + co]; \
        _Pragma("unroll") \
        for (int nt = 0; nt < 4; ++nt) \
            bq_[nt] = *(const bf16x8*)&sB[BUF][(wx*64 + nt*16 + l15) * 32 + co]; \
        _Pragma("unroll") \
        for (int mt = 0; mt < 4; ++mt) \
            _Pragma("unroll") \
            for (int nt = 0; nt < 4; ++nt) \
                acc[mt][nt] = __builtin_amdgcn_mfma_f32_16x16x32_bf16( \
                    af_[mt], bq_[nt], acc[mt][nt], 0, 0, 0); \
    } while (0)

    const int NT = K / 32;                 // 24 (even, >=4)
    STAGE(0);
    STAGE(1);
    VMBAR(4);

    #pragma unroll 1
    for (int p = 0; p <= NT - 4; p += 2) {
        COMPUTE(0);
        bar();
        STAGE(0);
        VMBAR(4);
        COMPUTE(1);
        bar();
        STAGE(1);
        VMBAR(4);
    }
    COMPUTE(0);
    VMBAR(0);
    COMPUTE(1);
#undef STAGE
#undef COMPUTE

    #pragma unroll
    for (int mt = 0; mt < 4; ++mt) {
        #pragma unroll
        for (int r = 0; r < 4; ++r) {
            int m = m0 + wy*64 + mt*16 + quad*4 + r;
            if (m >= M) continue;
            #pragma unroll
            for (int nt = 0; nt < 4; ++nt) {
                int n = n0 + wx*64 + nt*16 + l15;
                Cout[(size_t)m * N + n] = acc[mt][nt][r] + bias[n];
            }
        }
    }
}

// Attention (frozen from round 12): 8 waves x 16 q-rows (128 q/block),
// double-buffered swizzled reg-staging, clamp-free pointer bumps, f32 bias
// banks accumulated directly by QK^T MFMA, ones-MFMA row sums, wactive guard.
__global__ __launch_bounds__(512) void attn_kernel(
    const bf16* __restrict__ Kbuf, const bf16* __restrict__ VTbuf,
    const float* __restrict__ Bias, bf16* __restrict__ Hout)
{
    const int bh = blockIdx.x;                  // same-bh blocks land on one XCD (96%8==0)
    const int b = bh / NHEADS, h = bh % NHEADS;
    const int q0 = blockIdx.y * 128;
    const bf16* Kh  = Kbuf  + (size_t)bh * KSTRIDE * HD;   // [s][d]
    const bf16* VTh = VTbuf + (size_t)bh * HD * VSTRIDE;   // [d][s]

    __shared__ bf16 sK[2][64 * 64];    // 8 KB/buf
    __shared__ bf16 sVT[2][64 * 64];   // 8 KB/buf
    __shared__ bf16 sP[128 * 64];      // 16 KB -> 48 KB total (3 blocks/CU)

    const int t = threadIdx.x;
    const int w = t >> 6, l = t & 63, quad = l >> 4, l15 = l & 15;
    const int sw = l15 & 7;

    // wave-uniform: does this wave own any valid q-row?
    const bool wactive = (q0 + w * 16) < NSEQ;

    // staging geometry: 1 swizzled b128 chunk per thread per buffer
    const int r0 = t >> 3, c0 = t & 7;              // r0: 0..63, c0: 0..7
    const int dk0 = r0*64 + ((c0 ^ (r0 & 7)) << 3);

    // clamp-free global pointers (pure bumps; pads make every tile safe)
    const bf16* pK0 = Kh + (size_t)r0 * HD + c0 * 8;
    const bf16* pV0 = VTh + (size_t)r0 * VSTRIDE + c0 * 8;
    const float* pB = Bias + (size_t)(blockIdx.y*8 + w) * NJT * 1024 + quad*64 + l15*4;

    // Q fragments (B-operand), 16 query rows per wave; queries = keys.
    bf16x8 qf[2];
    {
        int row = q0 + w*16 + l15;              // < 1152, pad rows are zero
        #pragma unroll
        for (int ks = 0; ks < 2; ++ks)
            qf[ks] = *(const bf16x8*)&Kh[(size_t)row * HD + ks*32 + quad*8];
    }

    bf16x8 onesb;
    #pragma unroll
    for (int e = 0; e < 8; ++e) onesb[e] = (bf16)1.0f;

    f32x4 Oacc[4] = {};
    f32x4 Lacc = {};
    const int sPr0 = (w*16 + l15) * 64;

    uint4 kva, vva;
    f32x4 bpA[4], bpB[4];   // named bias banks (compile-time indexed)

#define PREFETCH_KV() do { \
        kva = *(const uint4*)pK0; \
        vva = *(const uint4*)pV0; \
        pK0 += 64*HD; pV0 += 64; \
    } while (0)

#define PREFETCH_B(BANK) do { \
        _Pragma("unroll") \
        for (int kt = 0; kt < 4; ++kt) \
            BANK[kt] = *(const f32x4*)(pB + kt*256); \
        pB += 1024; \
    } while (0)

#define ITER(CUR, ACC, NEXT) do { \
        *(uint4*)&sK[CUR][dk0] = kva; \
        *(uint4*)&sVT[CUR][dk0] = vva; \
        PREFETCH_KV(); \
        PREFETCH_B(NEXT); \
        bar(); \
        if (wactive) { \
            _Pragma("unroll") \
            for (int ks = 0; ks < 2; ++ks) { \
                bf16x8 af[4]; \
                _Pragma("unroll") \
                for (int kt = 0; kt < 4; ++kt) \
                    af[kt] = *(const bf16x8*)&sK[CUR][(kt*16 + l15)*64 + (((ks*4 + quad) ^ sw) << 3)]; \
                __builtin_amdgcn_s_setprio(1); \
                _Pragma("unroll") \
                for (int kt = 0; kt < 4; ++kt) \
                    ACC[kt] = __builtin_amdgcn_mfma_f32_16x16x32_bf16( \
                        af[kt], qf[ks], ACC[kt], 0, 0, 0); \
                __builtin_amdgcn_s_setprio(0); \
            } \
            _Pragma("unroll") \
            for (int kt = 0; kt < 4; ++kt) { \
                float p0 = __builtin_exp2f(ACC[kt][0]); \
                float p1 = __builtin_exp2f(ACC[kt][1]); \
                float p2 = __builtin_exp2f(ACC[kt][2]); \
                float p3 = __builtin_exp2f(ACC[kt][3]); \
                bf16x4 pv = { (bf16)p0, (bf16)p1, (bf16)p2, (bf16)p3 }; \
                int g = (kt*2 + (quad >> 1)) ^ sw; \
                *(bf16x4*)&sP[sPr0 + g*8 + (quad & 1)*4] = pv; \
            } \
            _Pragma("unroll") \
            for (int ks = 0; ks < 2; ++ks) { \
                bf16x8 bv[4]; \
                _Pragma("unroll") \
                for (int dt = 0; dt < 4; ++dt) \
                    bv[dt] = *(const bf16x8*)&sVT[CUR][(dt*16 + l15)*64 + (((ks*4 + quad) ^ sw) << 3)]; \
                __builtin_amdgcn_s_setprio(1); \
                bf16x8 ap = *(const bf16x8*)&sP[sPr0 + (((ks*4 + quad) ^ sw) * 8)]; \
                _Pragma("unroll") \
                for (int dt = 0; dt < 4; ++dt) \
                    Oacc[dt] = __builtin_amdgcn_mfma_f32_16x16x32_bf16( \
                        ap, bv[dt], Oacc[dt], 0, 0, 0); \
                Lacc = __builtin_amdgcn_mfma_f32_16x16x32_bf16( \
                    ap, onesb, Lacc, 0, 0, 0); \
                __builtin_amdgcn_s_setprio(0); \
            } \
        } \
    } while (0)

    PREFETCH_KV();        // tile 0 K/V
    PREFETCH_B(bpA);      // tile 0 bias -> bank A
    ITER(0, bpA, bpB);    // jt 0
    #pragma unroll 1
    for (int it = 0; it < (NJT - 1) / 2; ++it) {   // jt 1..16 as 8 pairs
        ITER(1, bpB, bpA);
        ITER(0, bpA, bpB);
    }
#undef ITER
#undef PREFETCH_KV
#undef PREFETCH_B

    // epilogue: Lacc holds per-row sums (rows quad*4+r) lane-locally
    #pragma unroll
    for (int r = 0; r < 4; ++r) {
        int g = q0 + w*16 + quad*4 + r;
        if (g >= NSEQ) continue;
        float inv = 1.f / Lacc[r];
        size_t base = ((size_t)(b * NSEQ) + g) * CDIM + h * HD;
        #pragma unroll
        for (int dt = 0; dt < 4; ++dt)
            Hout[base + dt*16 + l15] = (bf16)(Oacc[dt][r] * inv);
    }
}

extern "C" void kernel_launch(void* const* d_in, const int* in_sizes, int n_in,
                              void* d_out, int out_size, void* d_ws, size_t ws_size,
                              hipStream_t stream) {
    const float* x      = (const float*)d_in[0];
    const float* qkv_w  = (const float*)d_in[1];
    const float* qkv_b  = (const float*)d_in[2];
    const float* proj_w = (const float*)d_in[3];
    const float* proj_b = (const float*)d_in[4];
    float* out = (float*)d_out;

    char* ws = (char*)d_ws;
    const size_t XBF_BYTES   = (size_t)MROWS * CDIM * 2;                    // 12.68 MB
    const size_t WKV_BYTES   = (size_t)2 * CDIM * CDIM * 2;                 //  2.36 MB
    const size_t PW_BYTES    = (size_t)CDIM * CDIM * 2;                     //  1.18 MB
    const size_t BIAS_BYTES  = (size_t)NQ16 * NJT * 1024 * 4;               //  5.01 MB
    const size_t KBF_BYTES   = (size_t)BATCH * NHEADS * KSTRIDE * HD * 2;   // 14.16 MB

    bf16*  x_bf   = (bf16*)ws;
    bf16*  wkv_bf = (bf16*)(ws + XBF_BYTES);
    bf16*  pw_bf  = (bf16*)(ws + XBF_BYTES + WKV_BYTES);
    float* bias_t = (float*)(ws + XBF_BYTES + WKV_BYTES + PW_BYTES);
    bf16*  k_bf   = (bf16*)(ws + XBF_BYTES + WKV_BYTES + PW_BYTES + BIAS_BYTES);
    bf16*  vt_bf  = (bf16*)(ws + XBF_BYTES + WKV_BYTES + PW_BYTES + BIAS_BYTES + KBF_BYTES);
    // bias placed before k_bf so the harmless end-of-table bias over-read stays in-bounds

    // fused prep: f32 fragment-linear bias + all casts + K/V^T pad zeroing
    {
        int total = NQ16 * NJT * 1024 + MROWS * CDIM / 4
                  + 2 * CDIM * CDIM / 4 + CDIM * CDIM / 4
                  + BATCH * NHEADS * 120 * 8 + BATCH * NHEADS * 64 * 15;
        prep_kernel<<<dim3((total + 255) / 256), dim3(256), 0, stream>>>(
            x, qkv_w + (size_t)CDIM * CDIM, proj_w, x_bf, wkv_bf, pw_bf, bias_t,
            k_bf, vt_bf);
    }

    // qkv GEMM (k & v only): M=8256, N=1536, K=768 ; writes K' and V^T (padded)
    {
        dim3 grid(1536 / 128, (MROWS + 255) / 256);
        gemm_nt<1><<<grid, dim3(512), 0, stream>>>(x_bf, wkv_bf, qkv_b + CDIM,
                                                   nullptr, k_bf, vt_bf,
                                                   MROWS, 1536, CDIM);
    }

    // attention -> hidden (reuse x_bf buffer); grid (bh, 128-row qtile)
    {
        dim3 grid(BATCH * NHEADS, 9);
        attn_kernel<<<grid, dim3(512), 0, stream>>>(k_bf, vt_bf, bias_t, x_bf);
    }

    // proj GEMM: out = hidden @ proj_w^T + proj_b, fp32 out.
    // 128x128 tile -> 390 blocks (vs 198 at 256-tile: < 256 CUs, 1/4 GPU idle)
    {
        dim3 grid(CDIM / 128, (MROWS + 127) / 128);
        gemm_nt128<<<grid, dim3(256), 0, stream>>>(x_bf, pw_bf, proj_b,
                                                   out, MROWS, CDIM, CDIM);
    }
}